// Round 6
// baseline (165.163 us; speedup 1.0000x reference)
//
#include <hip/hip_runtime.h>

#define N_TOTAL 16384
#define HALF    8192
#define FEAT    128
#define MARGIN  0.3f
#define NBINS   1024   // NUM_IDS=1000 <= 1024

typedef __attribute__((ext_vector_type(8))) short  short8v;   // 8 x bf16 (4 VGPRs)
typedef __attribute__((ext_vector_type(4))) float  float4v;   // 4 x f32 acc

__device__ __forceinline__ unsigned short f32_to_bf16_rne(float f) {
    unsigned u = __float_as_uint(f);
    u += 0x7FFFu + ((u >> 16) & 1u);
    return (unsigned short)(u >> 16);
}

// ---- DPP cross-lane min/max within 16-lane rows (VALU pipe, not DS) ------
template<int CTRL>
__device__ __forceinline__ float dpp_mov_f(float x) {
    return __int_as_float(__builtin_amdgcn_update_dpp(
        0, __float_as_int(x), CTRL, 0xF, 0xF, true));
}
__device__ __forceinline__ float rowmin16(float x) {
    x = fminf(x, dpp_mov_f<0xB1>(x));    // quad_perm xor1
    x = fminf(x, dpp_mov_f<0x4E>(x));    // quad_perm xor2
    x = fminf(x, dpp_mov_f<0x141>(x));   // ROW_HALF_MIRROR
    x = fminf(x, dpp_mov_f<0x140>(x));   // ROW_MIRROR
    return x;
}
__device__ __forceinline__ float rowmax16(float x) {
    x = fmaxf(x, dpp_mov_f<0xB1>(x));
    x = fmaxf(x, dpp_mov_f<0x4E>(x));
    x = fmaxf(x, dpp_mov_f<0x141>(x));
    x = fmaxf(x, dpp_mov_f<0x140>(x));
    return x;
}

// ---------------------------------------------------------------------------
// histscan: 2 blocks x 1024 (one per modality half). LDS histogram + scan ->
// cursor (bucket starts). Block 0 zeroes accF/accI/ticket.
// ---------------------------------------------------------------------------
__global__ __launch_bounds__(1024) void histscan_kernel(
        const int* __restrict__ targets, int* __restrict__ cursor,
        int* __restrict__ accs /* [accF, accI, ticket] */) {
    __shared__ int lhist[NBINS];
    const int h = blockIdx.x;
    const int t = threadIdx.x;
    lhist[t] = 0;
    __syncthreads();
    const int* tg = targets + (h << 13);
    #pragma unroll
    for (int k = 0; k < 8; ++k)
        atomicAdd(&lhist[tg[k * 1024 + t]], 1);
    __syncthreads();
    const int lane = t & 63, wave = t >> 6;
    int x = lhist[t];
    const int orig = x;
    #pragma unroll
    for (int m = 1; m < 64; m <<= 1) {
        int v = __shfl_up(x, m, 64);
        if (lane >= m) x += v;
    }
    __shared__ int wsum[16];
    if (lane == 63) wsum[wave] = x;
    __syncthreads();
    if (t == 0) {
        int s = 0;
        for (int w = 0; w < 16; ++w) { int v = wsum[w]; wsum[w] = s; s += v; }
        if (h == 0) { accs[0] = 0; accs[1] = 0; accs[2] = 0; }
    }
    __syncthreads();
    cursor[(h << 10) + t] = x - orig + wsum[wave];
}

// ---------------------------------------------------------------------------
// prep: one wave per ORIGINAL row. Claims sorted slot, converts fp32->bf16,
// writes Xb in PANEL-MAJOR layout: panel p (16 rows) occupies 4096 B as
// [chunk 0..15][row 0..15][16 B]. Fragment loads in cross are then 64
// lanes x 16B contiguous (1 KB per instruction).
// ---------------------------------------------------------------------------
__global__ __launch_bounds__(256) void prep_kernel(
        const float* __restrict__ X, const int* __restrict__ targets,
        int* __restrict__ cursor,
        unsigned* __restrict__ Xb, float* __restrict__ sq, int* __restrict__ labs,
        int* __restrict__ maxpos, int* __restrict__ minneg) {
    const int wave = threadIdx.x >> 6, lane = threadIdx.x & 63;
    const int src = blockIdx.x * 4 + wave;          // original row
    const int h   = src >> 13;
    const int lbl = targets[src];
    int dst;
    if (lane == 0)
        dst = (h << 13) + atomicAdd(&cursor[(h << 10) + lbl], 1);
    dst = __shfl(dst, 0, 64);
    const float2 xv = ((const float2*)(X + (size_t)src * FEAT))[lane];
    unsigned short h0 = f32_to_bf16_rne(xv.x);      // k = 2*lane
    unsigned short h1 = f32_to_bf16_rne(xv.y);      // k = 2*lane+1
    // panel-major: uint index = panel*1024 + chunk*64 + (row%16)*4 + (lane%4)
    Xb[(dst >> 4) * 1024 + (lane >> 2) * 64 + (dst & 15) * 4 + (lane & 3)] =
        (unsigned)h0 | ((unsigned)h1 << 16);
    float x0 = __uint_as_float((unsigned)h0 << 16);
    float x1 = __uint_as_float((unsigned)h1 << 16);
    float p = x0 * x0 + x1 * x1;
    #pragma unroll
    for (int m = 1; m < 64; m <<= 1) p += __shfl_xor(p, m, 64);
    if (lane == 0) {
        sq[dst]     = p;
        labs[dst]   = lbl;
        maxpos[dst] = (int)0xFF800000u;   // -inf
        minneg[dst] = 0x7F800000;         // +inf
    }
}

// ---------------------------------------------------------------------------
// main: no LDS, no barriers. 512 blocks x 4 waves = 2048 waves (2/SIMD, all
// resident). Each wave owns a 64-col stripe (B frags resident in VGPRs,
// loaded once) and sweeps 8 row-tiles of 64x64, prefetching the next tile's
// A frags behind the epilogue. Col min/max accumulate in registers across
// tiles; one atomic per col at the end.
// ---------------------------------------------------------------------------
__global__ __launch_bounds__(256, 2) void cross_kernel(
        const unsigned short* __restrict__ Xb, const float* __restrict__ sq,
        const int* __restrict__ labs,
        int* __restrict__ maxpos, int* __restrict__ minneg) {
    const int t = threadIdx.x;
    const int wave = t >> 6, lane = t & 63;
    const int q = lane >> 4, c = lane & 15;
    const int slot   = blockIdx.x * 4 + wave;   // 0..2047
    const int stripe = slot >> 4;               // 0..127: 64-col stripe
    const int rc     = slot & 15;               // 0..15 : 8 row-tiles of 64

    const uint4* XbV = (const uint4*)Xb;        // panel p = 256 uint4s at p*256

    const float NEG_INF = __int_as_float((int)0xFF800000u);
    const float POS_INF = __int_as_float(0x7F800000);

    // ---- B stripe: cols HALF + stripe*64 .. +63 -> 4 panels, resident
    const int colbase = HALF + stripe * 64;
    const int pB0 = colbase >> 4;
    short8v bfr[4][4];                          // [tj][kk] = 64 VGPRs
    #pragma unroll
    for (int tj = 0; tj < 4; ++tj)
        #pragma unroll
        for (int kk = 0; kk < 4; ++kk)
            bfr[tj][kk] = *(const short8v*)&XbV[(pB0 + tj) * 256 + kk * 64 + lane];

    float sB[4]; int tB[4];
    #pragma unroll
    for (int tj = 0; tj < 4; ++tj) {
        sB[tj] = sq[colbase + tj * 16 + c];
        tB[tj] = labs[colbase + tj * 16 + c];
    }
    const int bMn = labs[colbase], bMx = labs[colbase + 63];

    float cmin[4], cmax[4];
    #pragma unroll
    for (int j = 0; j < 4; ++j) { cmin[j] = POS_INF; cmax[j] = NEG_INF; }

    // ---- prefetch tile 0's A frags
    short8v af[4][4];                           // [ti][kk]
    {
        const int pA0 = rc * 32;                // (rc*512)>>4
        #pragma unroll
        for (int ti = 0; ti < 4; ++ti)
            #pragma unroll
            for (int kk = 0; kk < 4; ++kk)
                af[ti][kk] = *(const short8v*)&XbV[(pA0 + ti) * 256 + kk * 64 + lane];
    }

    for (int tile = 0; tile < 8; ++tile) {
        const int rowbase = rc * 512 + tile * 64;

        // ---- MFMA 64x64
        float4v acc[4][4] = {};
        #pragma unroll
        for (int kk = 0; kk < 4; ++kk)
            #pragma unroll
            for (int ti = 0; ti < 4; ++ti)
                #pragma unroll
                for (int tj = 0; tj < 4; ++tj)
                    acc[ti][tj] = __builtin_amdgcn_mfma_f32_16x16x32_bf16(
                        af[ti][kk], bfr[tj][kk], acc[ti][tj], 0, 0, 0);

        // ---- prefetch next tile's A into af (latency hides behind epilogue)
        {
            const int ntile = (tile < 7) ? tile + 1 : 7;
            const int pA0 = rc * 32 + ntile * 4;
            #pragma unroll
            for (int ti = 0; ti < 4; ++ti)
                #pragma unroll
                for (int kk = 0; kk < 4; ++kk)
                    af[ti][kk] = *(const short8v*)&XbV[(pA0 + ti) * 256 + kk * 64 + lane];
        }

        // ---- epilogue: C layout col=c, row = q*4+reg
        float sA[16];
        #pragma unroll
        for (int ti = 0; ti < 4; ++ti)
            #pragma unroll
            for (int reg = 0; reg < 4; ++reg)
                sA[ti * 4 + reg] = sq[rowbase + ti * 16 + q * 4 + reg];

        const int aMin = labs[rowbase], aMax = labs[rowbase + 63];
        const bool overlap = (aMax >= bMn) && (bMx >= aMin);   // wave-uniform

        float rmin[16];
        #pragma unroll
        for (int i = 0; i < 16; ++i) rmin[i] = POS_INF;

        if (!overlap) {
            // fast path: every pair negative
            #pragma unroll
            for (int ti = 0; ti < 4; ++ti)
                #pragma unroll
                for (int tj = 0; tj < 4; ++tj)
                    #pragma unroll
                    for (int reg = 0; reg < 4; ++reg) {
                        int ri = ti * 4 + reg;
                        float d2 = fmaf(acc[ti][tj][reg], -2.0f, sA[ri] + sB[tj]);
                        rmin[ri] = fminf(rmin[ri], d2);
                        cmin[tj] = fminf(cmin[tj], d2);
                    }
            #pragma unroll
            for (int i = 0; i < 16; ++i) rmin[i] = rowmin16(rmin[i]);
            if (c == 0) {
                #pragma unroll
                for (int ti = 0; ti < 4; ++ti)
                    #pragma unroll
                    for (int reg = 0; reg < 4; ++reg)
                        atomicMin(&minneg[rowbase + ti * 16 + q * 4 + reg],
                                  __float_as_int(rmin[ti * 4 + reg]));
            }
        } else {
            // slow path: labels may match
            int tA[16];
            #pragma unroll
            for (int ti = 0; ti < 4; ++ti)
                #pragma unroll
                for (int reg = 0; reg < 4; ++reg)
                    tA[ti * 4 + reg] = labs[rowbase + ti * 16 + q * 4 + reg];
            float rmax[16];
            #pragma unroll
            for (int i = 0; i < 16; ++i) rmax[i] = NEG_INF;

            #pragma unroll
            for (int ti = 0; ti < 4; ++ti)
                #pragma unroll
                for (int tj = 0; tj < 4; ++tj)
                    #pragma unroll
                    for (int reg = 0; reg < 4; ++reg) {
                        int ri = ti * 4 + reg;
                        float d2 = fmaf(acc[ti][tj][reg], -2.0f, sA[ri] + sB[tj]);
                        bool same = (tA[ri] == tB[tj]);
                        float posc = same ? d2 : NEG_INF;
                        float negc = same ? POS_INF : d2;
                        rmax[ri] = fmaxf(rmax[ri], posc);
                        cmax[tj] = fmaxf(cmax[tj], posc);
                        rmin[ri] = fminf(rmin[ri], negc);
                        cmin[tj] = fminf(cmin[tj], negc);
                    }
            #pragma unroll
            for (int i = 0; i < 16; ++i) {
                rmin[i] = rowmin16(rmin[i]);
                rmax[i] = rowmax16(rmax[i]);
            }
            if (c == 0) {
                #pragma unroll
                for (int ti = 0; ti < 4; ++ti)
                    #pragma unroll
                    for (int reg = 0; reg < 4; ++reg) {
                        int gi = rowbase + ti * 16 + q * 4 + reg;
                        atomicMin(&minneg[gi], __float_as_int(rmin[ti * 4 + reg]));
                        atomicMax(&maxpos[gi], __float_as_int(rmax[ti * 4 + reg]));
                    }
            }
        }
    }

    // ---- col results: reduce across q-groups, one atomic per col
    #pragma unroll
    for (int m = 16; m <= 32; m <<= 1)
        #pragma unroll
        for (int j = 0; j < 4; ++j) {
            cmin[j] = fminf(cmin[j], __shfl_xor(cmin[j], m, 64));
            cmax[j] = fmaxf(cmax[j], __shfl_xor(cmax[j], m, 64));
        }
    if (q == 0) {
        #pragma unroll
        for (int tj = 0; tj < 4; ++tj) {
            int gj = colbase + tj * 16 + c;
            atomicMin(&minneg[gj], __float_as_int(cmin[tj]));
            atomicMax(&maxpos[gj], __float_as_int(cmax[tj]));
        }
    }
}

// ---------------------------------------------------------------------------
// final: per-row loss terms -> global accumulators; LAST block (ticket)
// writes d_out.
// ---------------------------------------------------------------------------
__global__ __launch_bounds__(256) void final_kernel(
        const int* __restrict__ maxpos, const int* __restrict__ minneg,
        int* __restrict__ accs /* [accF, accI, ticket] */,
        float* __restrict__ out) {
    const int i = blockIdx.x * 256 + threadIdx.x;
    const int t = threadIdx.x;
    float* accF  = (float*)&accs[0];
    int*   accI  = &accs[1];
    int*   tick  = &accs[2];
    float ap = sqrtf(fmaxf(__int_as_float(maxpos[i]), 1e-12f));
    float an = sqrtf(fmaxf(__int_as_float(minneg[i]), 1e-12f));
    float term = fmaxf(ap - an + MARGIN, 0.0f);
    int cnt = (an >= ap) ? 1 : 0;
    #pragma unroll
    for (int m = 1; m < 64; m <<= 1) {
        term += __shfl_xor(term, m, 64);
        cnt  += __shfl_xor(cnt, m, 64);
    }
    __shared__ float sf[4];
    __shared__ int   si[4];
    if ((t & 63) == 0) { sf[t >> 6] = term; si[t >> 6] = cnt; }
    __syncthreads();
    if (t == 0) {
        atomicAdd(accF, sf[0] + sf[1] + sf[2] + sf[3]);
        atomicAdd(accI, si[0] + si[1] + si[2] + si[3]);
        __threadfence();
        int old = atomicAdd(tick, 1);
        if (old == gridDim.x - 1) {
            __threadfence();
            float S = atomicAdd(accF, 0.0f);
            int   C = atomicAdd(accI, 0);
            out[0] = S / (float)N_TOTAL;
            out[1] = (float)C;
        }
    }
}

extern "C" void kernel_launch(void* const* d_in, const int* in_sizes, int n_in,
                              void* d_out, int out_size, void* d_ws, size_t ws_size,
                              hipStream_t stream) {
    const float* X       = (const float*)d_in[0];   // [16384,128] fp32
    const int*   targets = (const int*)d_in[1];     // [16384] int32
    float* out = (float*)d_out;                     // [2]: loss, correct

    char* ws = (char*)d_ws;
    const size_t XB_BYTES = (size_t)N_TOTAL * FEAT * 2;              // 4 MB
    unsigned* Xb  = (unsigned*)ws;
    float* sq     = (float*)(ws + XB_BYTES);                         // 64 KB
    int* maxpos   = (int*)(ws + XB_BYTES + 1 * 65536);               // 64 KB
    int* minneg   = (int*)(ws + XB_BYTES + 2 * 65536);               // 64 KB
    int* labs     = (int*)(ws + XB_BYTES + 3 * 65536);               // 64 KB
    int* cursor   = (int*)(ws + XB_BYTES + 4 * 65536);               // 8 KB
    int* accs     = cursor + 2 * NBINS;                              // 12 B

    histscan_kernel<<<2, 1024, 0, stream>>>(targets, cursor, accs);
    prep_kernel    <<<4096, 256, 0, stream>>>(X, targets, cursor, Xb, sq, labs,
                                              maxpos, minneg);
    cross_kernel   <<<512, 256, 0, stream>>>(
        (const unsigned short*)Xb, sq, labs, maxpos, minneg);
    final_kernel   <<<64, 256, 0, stream>>>(maxpos, minneg, accs, out);
}

// Round 7
// 111.615 us; speedup vs baseline: 1.4797x; 1.4797x over previous
//
#include <hip/hip_runtime.h>

#define N_TOTAL 16384
#define HALF    8192
#define FEAT    128
#define MARGIN  0.3f
#define NBINS   1024   // NUM_IDS=1000 <= 1024

typedef __attribute__((ext_vector_type(8))) short  short8v;   // 8 x bf16 (4 VGPRs)
typedef __attribute__((ext_vector_type(4))) float  float4v;   // 4 x f32 acc

__device__ __forceinline__ unsigned short f32_to_bf16_rne(float f) {
    unsigned u = __float_as_uint(f);
    u += 0x7FFFu + ((u >> 16) & 1u);
    return (unsigned short)(u >> 16);
}

// ---- DPP cross-lane min/max within 16-lane rows (VALU pipe, not DS) ------
template<int CTRL>
__device__ __forceinline__ float dpp_mov_f(float x) {
    return __int_as_float(__builtin_amdgcn_update_dpp(
        0, __float_as_int(x), CTRL, 0xF, 0xF, true));
}
__device__ __forceinline__ float rowmin16(float x) {
    x = fminf(x, dpp_mov_f<0xB1>(x));    // quad_perm xor1
    x = fminf(x, dpp_mov_f<0x4E>(x));    // quad_perm xor2
    x = fminf(x, dpp_mov_f<0x141>(x));   // ROW_HALF_MIRROR
    x = fminf(x, dpp_mov_f<0x140>(x));   // ROW_MIRROR
    return x;
}
__device__ __forceinline__ float rowmax16(float x) {
    x = fmaxf(x, dpp_mov_f<0xB1>(x));
    x = fmaxf(x, dpp_mov_f<0x4E>(x));
    x = fmaxf(x, dpp_mov_f<0x141>(x));
    x = fmaxf(x, dpp_mov_f<0x140>(x));
    return x;
}

// ---------------------------------------------------------------------------
// histscan: 2 blocks x 1024 (one per modality half). LDS histogram + scan ->
// cursor (bucket starts). Block 0 zeroes accF/accI/ticket.
// ---------------------------------------------------------------------------
__global__ __launch_bounds__(1024) void histscan_kernel(
        const int* __restrict__ targets, int* __restrict__ cursor,
        int* __restrict__ accs /* [accF, accI, ticket] */) {
    __shared__ int lhist[NBINS];
    const int h = blockIdx.x;
    const int t = threadIdx.x;
    lhist[t] = 0;
    __syncthreads();
    const int* tg = targets + (h << 13);
    #pragma unroll
    for (int k = 0; k < 8; ++k)
        atomicAdd(&lhist[tg[k * 1024 + t]], 1);
    __syncthreads();
    const int lane = t & 63, wave = t >> 6;
    int x = lhist[t];
    const int orig = x;
    #pragma unroll
    for (int m = 1; m < 64; m <<= 1) {
        int v = __shfl_up(x, m, 64);
        if (lane >= m) x += v;
    }
    __shared__ int wsum[16];
    if (lane == 63) wsum[wave] = x;
    __syncthreads();
    if (t == 0) {
        int s = 0;
        for (int w = 0; w < 16; ++w) { int v = wsum[w]; wsum[w] = s; s += v; }
        if (h == 0) { accs[0] = 0; accs[1] = 0; accs[2] = 0; }
    }
    __syncthreads();
    cursor[(h << 10) + t] = x - orig + wsum[wave];
}

// ---------------------------------------------------------------------------
// prep: one wave per ORIGINAL row. Claims sorted slot, converts fp32->bf16,
// writes Xb in PANEL-MAJOR layout (panel = 16 rows: [chunk][row][16B]).
// ---------------------------------------------------------------------------
__global__ __launch_bounds__(256) void prep_kernel(
        const float* __restrict__ X, const int* __restrict__ targets,
        int* __restrict__ cursor,
        unsigned* __restrict__ Xb, float* __restrict__ sq, int* __restrict__ labs) {
    const int wave = threadIdx.x >> 6, lane = threadIdx.x & 63;
    const int src = blockIdx.x * 4 + wave;          // original row
    const int h   = src >> 13;
    const int lbl = targets[src];
    int dst;
    if (lane == 0)
        dst = (h << 13) + atomicAdd(&cursor[(h << 10) + lbl], 1);
    dst = __shfl(dst, 0, 64);
    const float2 xv = ((const float2*)(X + (size_t)src * FEAT))[lane];
    unsigned short h0 = f32_to_bf16_rne(xv.x);      // k = 2*lane
    unsigned short h1 = f32_to_bf16_rne(xv.y);      // k = 2*lane+1
    Xb[(dst >> 4) * 1024 + (lane >> 2) * 64 + (dst & 15) * 4 + (lane & 3)] =
        (unsigned)h0 | ((unsigned)h1 << 16);
    float x0 = __uint_as_float((unsigned)h0 << 16);
    float x1 = __uint_as_float((unsigned)h1 << 16);
    float p = x0 * x0 + x1 * x1;
    #pragma unroll
    for (int m = 1; m < 64; m <<= 1) p += __shfl_xor(p, m, 64);
    if (lane == 0) {
        sq[dst]   = p;
        labs[dst] = lbl;
    }
}

// ---------------------------------------------------------------------------
// main: 2 symmetric passes in one launch, NO atomics, NO LDS, NO barriers.
// Wave owns 64 rows of its half (A frags resident, 16 KB in VGPRs) and
// sweeps 16 col-tiles (1024 cols) of the other half, register-accumulating
// min-over-negatives and max-over-positives per row. One DPP reduce + plain
// stores to partial arrays at the end. 2048 waves = 2/SIMD, all resident.
// Block's 4 waves = 4 adjacent row-tiles, same col-chunk -> B tiles hit L1.
// ---------------------------------------------------------------------------
__global__ __launch_bounds__(256, 2) void cross_kernel(
        const unsigned short* __restrict__ Xb, const float* __restrict__ sq,
        const int* __restrict__ labs,
        float* __restrict__ pmin, float* __restrict__ pmax) {
    const int t = threadIdx.x;
    const int wave = t >> 6, lane = t & 63;
    const int q = lane >> 4, c = lane & 15;
    const int b    = blockIdx.x;            // 0..511
    const int pass = b >> 8;                // 0: rows=half0, 1: rows=half1
    const int bb   = b & 255;
    const int cc   = bb & 7;                // col-chunk (1024 cols)
    const int rt   = (bb >> 3) * 4 + wave;  // row-tile 0..127
    const int own  = pass ? HALF : 0;
    const int oth  = pass ? 0 : HALF;
    const int ownbase = own + rt * 64;

    const uint4* XbV = (const uint4*)Xb;    // panel p = 256 uint4 at p*256

    const float NEG_INF = __int_as_float((int)0xFF800000u);
    const float POS_INF = __int_as_float(0x7F800000);

    // ---- resident A: 64 own rows (4 panels), 64 VGPRs
    short8v af[4][4];                       // [ti][kk]
    const int pA0 = ownbase >> 4;
    #pragma unroll
    for (int ti = 0; ti < 4; ++ti)
        #pragma unroll
        for (int kk = 0; kk < 4; ++kk)
            af[ti][kk] = *(const short8v*)&XbV[(pA0 + ti) * 256 + kk * 64 + lane];

    const int aMin = labs[ownbase], aMax = labs[ownbase + 63];

    float rmin[16], rmax[16];               // per own row (excl. sA term)
    #pragma unroll
    for (int i = 0; i < 16; ++i) { rmin[i] = POS_INF; rmax[i] = NEG_INF; }

    for (int tile = 0; tile < 16; ++tile) {
        const int colbase = oth + cc * 1024 + tile * 64;
        const int bMn = labs[colbase], bMx = labs[colbase + 63];
        const bool overlap = (aMax >= bMn) && (bMx >= aMin);   // wave-uniform

        #pragma unroll
        for (int hh = 0; hh < 2; ++hh) {    // 32-col subtile (register economy)
            const int sub = colbase + hh * 32;
            const int pB0 = sub >> 4;
            short8v bfr[2][4];
            #pragma unroll
            for (int tj = 0; tj < 2; ++tj)
                #pragma unroll
                for (int kk = 0; kk < 4; ++kk)
                    bfr[tj][kk] = *(const short8v*)&XbV[(pB0 + tj) * 256 + kk * 64 + lane];
            float sB[2];
            #pragma unroll
            for (int tj = 0; tj < 2; ++tj)
                sB[tj] = sq[sub + tj * 16 + c];

            float4v acc[4][2] = {};
            #pragma unroll
            for (int kk = 0; kk < 4; ++kk)
                #pragma unroll
                for (int ti = 0; ti < 4; ++ti)
                    #pragma unroll
                    for (int tj = 0; tj < 2; ++tj)
                        acc[ti][tj] = __builtin_amdgcn_mfma_f32_16x16x32_bf16(
                            af[ti][kk], bfr[tj][kk], acc[ti][tj], 0, 0, 0);

            if (!overlap) {
                // fast path: every pair negative; v = sB - 2*dot
                #pragma unroll
                for (int ti = 0; ti < 4; ++ti)
                    #pragma unroll
                    for (int tj = 0; tj < 2; ++tj)
                        #pragma unroll
                        for (int reg = 0; reg < 4; ++reg) {
                            float v = fmaf(acc[ti][tj][reg], -2.0f, sB[tj]);
                            rmin[ti * 4 + reg] = fminf(rmin[ti * 4 + reg], v);
                        }
            } else {
                int tB[2];
                #pragma unroll
                for (int tj = 0; tj < 2; ++tj)
                    tB[tj] = labs[sub + tj * 16 + c];
                int tA[16];
                #pragma unroll
                for (int ti = 0; ti < 4; ++ti)
                    #pragma unroll
                    for (int reg = 0; reg < 4; ++reg)
                        tA[ti * 4 + reg] = labs[ownbase + ti * 16 + q * 4 + reg];
                #pragma unroll
                for (int ti = 0; ti < 4; ++ti)
                    #pragma unroll
                    for (int tj = 0; tj < 2; ++tj)
                        #pragma unroll
                        for (int reg = 0; reg < 4; ++reg) {
                            int ri = ti * 4 + reg;
                            float v = fmaf(acc[ti][tj][reg], -2.0f, sB[tj]);
                            bool same = (tA[ri] == tB[tj]);
                            rmin[ri] = fminf(rmin[ri], same ? POS_INF : v);
                            rmax[ri] = fmaxf(rmax[ri], same ? v : NEG_INF);
                        }
            }
        }
    }

    // ---- finalize: reduce across the 16 c-lanes, add ||own row||^2, store
    #pragma unroll
    for (int i = 0; i < 16; ++i) {
        rmin[i] = rowmin16(rmin[i]);
        rmax[i] = rowmax16(rmax[i]);
    }
    if (c == 0) {
        #pragma unroll
        for (int ti = 0; ti < 4; ++ti)
            #pragma unroll
            for (int reg = 0; reg < 4; ++reg) {
                int gi = ownbase + ti * 16 + q * 4 + reg;
                float sA = sq[gi];
                pmin[cc * N_TOTAL + gi] = sA + rmin[ti * 4 + reg]; // +inf stays +inf
                pmax[cc * N_TOTAL + gi] = sA + rmax[ti * 4 + reg]; // -inf stays -inf
            }
    }
}

// ---------------------------------------------------------------------------
// final: reduce the 8 partials per row, loss terms -> global accumulators;
// LAST block (ticket) writes d_out.
// ---------------------------------------------------------------------------
__global__ __launch_bounds__(256) void final_kernel(
        const float* __restrict__ pmin, const float* __restrict__ pmax,
        int* __restrict__ accs /* [accF, accI, ticket] */,
        float* __restrict__ out) {
    const int i = blockIdx.x * 256 + threadIdx.x;
    const int t = threadIdx.x;
    float* accF = (float*)&accs[0];
    int*   accI = &accs[1];
    int*   tick = &accs[2];
    float an2 = pmin[i], ap2 = pmax[i];
    #pragma unroll
    for (int ccp = 1; ccp < 8; ++ccp) {
        an2 = fminf(an2, pmin[ccp * N_TOTAL + i]);
        ap2 = fmaxf(ap2, pmax[ccp * N_TOTAL + i]);
    }
    float ap = sqrtf(fmaxf(ap2, 1e-12f));
    float an = sqrtf(fmaxf(an2, 1e-12f));
    float term = fmaxf(ap - an + MARGIN, 0.0f);
    int cnt = (an >= ap) ? 1 : 0;
    #pragma unroll
    for (int m = 1; m < 64; m <<= 1) {
        term += __shfl_xor(term, m, 64);
        cnt  += __shfl_xor(cnt, m, 64);
    }
    __shared__ float sf[4];
    __shared__ int   si[4];
    if ((t & 63) == 0) { sf[t >> 6] = term; si[t >> 6] = cnt; }
    __syncthreads();
    if (t == 0) {
        atomicAdd(accF, sf[0] + sf[1] + sf[2] + sf[3]);
        atomicAdd(accI, si[0] + si[1] + si[2] + si[3]);
        __threadfence();
        int old = atomicAdd(tick, 1);
        if (old == gridDim.x - 1) {
            __threadfence();
            float S = atomicAdd(accF, 0.0f);
            int   C = atomicAdd(accI, 0);
            out[0] = S / (float)N_TOTAL;
            out[1] = (float)C;
        }
    }
}

extern "C" void kernel_launch(void* const* d_in, const int* in_sizes, int n_in,
                              void* d_out, int out_size, void* d_ws, size_t ws_size,
                              hipStream_t stream) {
    const float* X       = (const float*)d_in[0];   // [16384,128] fp32
    const int*   targets = (const int*)d_in[1];     // [16384] int32
    float* out = (float*)d_out;                     // [2]: loss, correct

    char* ws = (char*)d_ws;
    const size_t XB_BYTES = (size_t)N_TOTAL * FEAT * 2;              // 4 MB
    unsigned* Xb  = (unsigned*)ws;
    float* sq     = (float*)(ws + XB_BYTES);                         // 64 KB
    int* labs     = (int*)(ws + XB_BYTES + 1 * 65536);               // 64 KB
    float* pmin   = (float*)(ws + XB_BYTES + 2 * 65536);             // 512 KB
    float* pmax   = (float*)(ws + XB_BYTES + 2 * 65536 + 8 * N_TOTAL * 4); // 512 KB
    int* cursor   = (int*)(ws + XB_BYTES + 2 * 65536 + 16 * N_TOTAL * 4);  // 8 KB
    int* accs     = cursor + 2 * NBINS;                              // 12 B

    histscan_kernel<<<2, 1024, 0, stream>>>(targets, cursor, accs);
    prep_kernel    <<<4096, 256, 0, stream>>>(X, targets, cursor, Xb, sq, labs);
    cross_kernel   <<<512, 256, 0, stream>>>(
        (const unsigned short*)Xb, sq, labs, pmin, pmax);
    final_kernel   <<<64, 256, 0, stream>>>(pmin, pmax, accs, out);
}

// Round 8
// 110.922 us; speedup vs baseline: 1.4890x; 1.0062x over previous
//
#include <hip/hip_runtime.h>

#define N_TOTAL 16384
#define HALF    8192
#define FEAT    128
#define MARGIN  0.3f
#define NBINS   1024   // NUM_IDS=1000 <= 1024

typedef __attribute__((ext_vector_type(8))) short  short8v;   // 8 x bf16 (4 VGPRs)
typedef __attribute__((ext_vector_type(4))) float  float4v;   // 4 x f32 acc

__device__ __forceinline__ unsigned short f32_to_bf16_rne(float f) {
    unsigned u = __float_as_uint(f);
    u += 0x7FFFu + ((u >> 16) & 1u);
    return (unsigned short)(u >> 16);
}

// ---- DPP cross-lane min/max within 16-lane rows (VALU pipe, not DS) ------
template<int CTRL>
__device__ __forceinline__ float dpp_mov_f(float x) {
    return __int_as_float(__builtin_amdgcn_update_dpp(
        0, __float_as_int(x), CTRL, 0xF, 0xF, true));
}
__device__ __forceinline__ float rowmin16(float x) {
    x = fminf(x, dpp_mov_f<0xB1>(x));    // quad_perm xor1
    x = fminf(x, dpp_mov_f<0x4E>(x));    // quad_perm xor2
    x = fminf(x, dpp_mov_f<0x141>(x));   // ROW_HALF_MIRROR
    x = fminf(x, dpp_mov_f<0x140>(x));   // ROW_MIRROR
    return x;
}
__device__ __forceinline__ float rowmax16(float x) {
    x = fmaxf(x, dpp_mov_f<0xB1>(x));
    x = fmaxf(x, dpp_mov_f<0x4E>(x));
    x = fmaxf(x, dpp_mov_f<0x141>(x));
    x = fmaxf(x, dpp_mov_f<0x140>(x));
    return x;
}

// ---------------------------------------------------------------------------
// histscan: 2 blocks x 1024 (one per modality half). LDS histogram + scan ->
// cursor (bucket starts). Block 0 zeroes accF/accI/ticket.
// ---------------------------------------------------------------------------
__global__ __launch_bounds__(1024) void histscan_kernel(
        const int* __restrict__ targets, int* __restrict__ cursor,
        int* __restrict__ accs /* [accF, accI, ticket] */) {
    __shared__ int lhist[NBINS];
    const int h = blockIdx.x;
    const int t = threadIdx.x;
    lhist[t] = 0;
    __syncthreads();
    const int* tg = targets + (h << 13);
    #pragma unroll
    for (int k = 0; k < 8; ++k)
        atomicAdd(&lhist[tg[k * 1024 + t]], 1);
    __syncthreads();
    const int lane = t & 63, wave = t >> 6;
    int x = lhist[t];
    const int orig = x;
    #pragma unroll
    for (int m = 1; m < 64; m <<= 1) {
        int v = __shfl_up(x, m, 64);
        if (lane >= m) x += v;
    }
    __shared__ int wsum[16];
    if (lane == 63) wsum[wave] = x;
    __syncthreads();
    if (t == 0) {
        int s = 0;
        for (int w = 0; w < 16; ++w) { int v = wsum[w]; wsum[w] = s; s += v; }
        if (h == 0) { accs[0] = 0; accs[1] = 0; accs[2] = 0; }
    }
    __syncthreads();
    cursor[(h << 10) + t] = x - orig + wsum[wave];
}

// ---------------------------------------------------------------------------
// prep: one wave per ORIGINAL row. Claims sorted slot, converts fp32->bf16,
// writes Xb in PANEL-MAJOR layout (panel = 16 rows: [chunk][row][16B]).
// ---------------------------------------------------------------------------
__global__ __launch_bounds__(256) void prep_kernel(
        const float* __restrict__ X, const int* __restrict__ targets,
        int* __restrict__ cursor,
        unsigned* __restrict__ Xb, float* __restrict__ sq, int* __restrict__ labs) {
    const int wave = threadIdx.x >> 6, lane = threadIdx.x & 63;
    const int src = blockIdx.x * 4 + wave;          // original row
    const int h   = src >> 13;
    const int lbl = targets[src];
    int dst;
    if (lane == 0)
        dst = (h << 13) + atomicAdd(&cursor[(h << 10) + lbl], 1);
    dst = __shfl(dst, 0, 64);
    const float2 xv = ((const float2*)(X + (size_t)src * FEAT))[lane];
    unsigned short h0 = f32_to_bf16_rne(xv.x);      // k = 2*lane
    unsigned short h1 = f32_to_bf16_rne(xv.y);      // k = 2*lane+1
    Xb[(dst >> 4) * 1024 + (lane >> 2) * 64 + (dst & 15) * 4 + (lane & 3)] =
        (unsigned)h0 | ((unsigned)h1 << 16);
    float x0 = __uint_as_float((unsigned)h0 << 16);
    float x1 = __uint_as_float((unsigned)h1 << 16);
    float p = x0 * x0 + x1 * x1;
    #pragma unroll
    for (int m = 1; m < 64; m <<= 1) p += __shfl_xor(p, m, 64);
    if (lane == 0) {
        sq[dst]   = p;
        labs[dst] = lbl;
    }
}

// ---------------------------------------------------------------------------
// main: 2 symmetric passes, no atomics/LDS/barriers. Wave owns 64 rows
// (A frags resident in VGPRs) and sweeps 32 subtiles of 32 cols each
// (1024 cols), SOFTWARE-PIPELINED: B subtile s+1 is in flight while MFMA
// runs on subtile s (double buffer). Register-accumulated min/max, DPP
// reduce, plain stores to partials. 2048 waves = 2/SIMD, all resident.
// ---------------------------------------------------------------------------
__global__ __launch_bounds__(256, 2) void cross_kernel(
        const unsigned short* __restrict__ Xb, const float* __restrict__ sq,
        const int* __restrict__ labs,
        float* __restrict__ pmin, float* __restrict__ pmax) {
    const int t = threadIdx.x;
    const int wave = t >> 6, lane = t & 63;
    const int q = lane >> 4, c = lane & 15;
    const int b    = blockIdx.x;            // 0..511
    const int pass = b >> 8;                // 0: rows=half0, 1: rows=half1
    const int bb   = b & 255;
    const int cc   = bb & 7;                // col-chunk (1024 cols)
    const int rt   = (bb >> 3) * 4 + wave;  // row-tile 0..127
    const int own  = pass ? HALF : 0;
    const int oth  = pass ? 0 : HALF;
    const int ownbase = own + rt * 64;
    const int chunk0  = oth + cc * 1024;    // first col of this wave's sweep

    const uint4* XbV = (const uint4*)Xb;    // panel p = 256 uint4 at p*256

    const float NEG_INF = __int_as_float((int)0xFF800000u);
    const float POS_INF = __int_as_float(0x7F800000);

    // ---- resident A: 64 own rows (4 panels), 64 VGPRs
    short8v af[4][4];                       // [ti][kk]
    const int pA0 = ownbase >> 4;
    #pragma unroll
    for (int ti = 0; ti < 4; ++ti)
        #pragma unroll
        for (int kk = 0; kk < 4; ++kk)
            af[ti][kk] = *(const short8v*)&XbV[(pA0 + ti) * 256 + kk * 64 + lane];

    const int aMin = labs[ownbase], aMax = labs[ownbase + 63];

    float rmin[16], rmax[16];               // per own row (excl. sA term)
    #pragma unroll
    for (int i = 0; i < 16; ++i) { rmin[i] = POS_INF; rmax[i] = NEG_INF; }

    // ---- pipelined B sweep: 32 subtiles of 32 cols
    auto loadsub = [&](int s, short8v (&bfr)[2][4], float (&sB)[2]) {
        const int sub = chunk0 + s * 32;
        const int pB0 = sub >> 4;
        #pragma unroll
        for (int tj = 0; tj < 2; ++tj) {
            #pragma unroll
            for (int kk = 0; kk < 4; ++kk)
                bfr[tj][kk] = *(const short8v*)&XbV[(pB0 + tj) * 256 + kk * 64 + lane];
            sB[tj] = sq[sub + tj * 16 + c];
        }
    };
    auto computesub = [&](int s, short8v (&bfr)[2][4], float (&sB)[2]) {
        const int sub = chunk0 + s * 32;
        const bool overlap = (aMax >= labs[sub]) && (labs[sub + 31] >= aMin);

        float4v acc[4][2] = {};
        #pragma unroll
        for (int kk = 0; kk < 4; ++kk)
            #pragma unroll
            for (int ti = 0; ti < 4; ++ti)
                #pragma unroll
                for (int tj = 0; tj < 2; ++tj)
                    acc[ti][tj] = __builtin_amdgcn_mfma_f32_16x16x32_bf16(
                        af[ti][kk], bfr[tj][kk], acc[ti][tj], 0, 0, 0);

        if (!overlap) {                     // fast path: all pairs negative
            #pragma unroll
            for (int ti = 0; ti < 4; ++ti)
                #pragma unroll
                for (int tj = 0; tj < 2; ++tj)
                    #pragma unroll
                    for (int reg = 0; reg < 4; ++reg) {
                        float v = fmaf(acc[ti][tj][reg], -2.0f, sB[tj]);
                        rmin[ti * 4 + reg] = fminf(rmin[ti * 4 + reg], v);
                    }
        } else {                            // slow path: labels may match
            int tB[2];
            #pragma unroll
            for (int tj = 0; tj < 2; ++tj)
                tB[tj] = labs[sub + tj * 16 + c];
            int tA[16];
            #pragma unroll
            for (int ti = 0; ti < 4; ++ti)
                #pragma unroll
                for (int reg = 0; reg < 4; ++reg)
                    tA[ti * 4 + reg] = labs[ownbase + ti * 16 + q * 4 + reg];
            #pragma unroll
            for (int ti = 0; ti < 4; ++ti)
                #pragma unroll
                for (int tj = 0; tj < 2; ++tj)
                    #pragma unroll
                    for (int reg = 0; reg < 4; ++reg) {
                        int ri = ti * 4 + reg;
                        float v = fmaf(acc[ti][tj][reg], -2.0f, sB[tj]);
                        bool same = (tA[ri] == tB[tj]);
                        rmin[ri] = fminf(rmin[ri], same ? POS_INF : v);
                        rmax[ri] = fmaxf(rmax[ri], same ? v : NEG_INF);
                    }
        }
    };

    short8v bA[2][4], bB[2][4];
    float   sA2[2],   sB2[2];
    loadsub(0, bA, sA2);
    for (int s = 0; s < 32; s += 2) {
        loadsub(s + 1, bB, sB2);            // in flight during compute(bA)
        computesub(s, bA, sA2);
        if (s + 2 < 32) loadsub(s + 2, bA, sA2);  // in flight during compute(bB)
        computesub(s + 1, bB, sB2);
    }

    // ---- finalize: reduce across the 16 c-lanes, add ||own row||^2, store
    #pragma unroll
    for (int i = 0; i < 16; ++i) {
        rmin[i] = rowmin16(rmin[i]);
        rmax[i] = rowmax16(rmax[i]);
    }
    if (c == 0) {
        #pragma unroll
        for (int ti = 0; ti < 4; ++ti)
            #pragma unroll
            for (int reg = 0; reg < 4; ++reg) {
                int gi = ownbase + ti * 16 + q * 4 + reg;
                float sA = sq[gi];
                pmin[cc * N_TOTAL + gi] = sA + rmin[ti * 4 + reg]; // +inf stays +inf
                pmax[cc * N_TOTAL + gi] = sA + rmax[ti * 4 + reg]; // -inf stays -inf
            }
    }
}

// ---------------------------------------------------------------------------
// final: reduce the 8 partials per row, loss terms -> global accumulators;
// LAST block (ticket) writes d_out.
// ---------------------------------------------------------------------------
__global__ __launch_bounds__(256) void final_kernel(
        const float* __restrict__ pmin, const float* __restrict__ pmax,
        int* __restrict__ accs /* [accF, accI, ticket] */,
        float* __restrict__ out) {
    const int i = blockIdx.x * 256 + threadIdx.x;
    const int t = threadIdx.x;
    float* accF = (float*)&accs[0];
    int*   accI = &accs[1];
    int*   tick = &accs[2];
    float an2 = pmin[i], ap2 = pmax[i];
    #pragma unroll
    for (int ccp = 1; ccp < 8; ++ccp) {
        an2 = fminf(an2, pmin[ccp * N_TOTAL + i]);
        ap2 = fmaxf(ap2, pmax[ccp * N_TOTAL + i]);
    }
    float ap = sqrtf(fmaxf(ap2, 1e-12f));
    float an = sqrtf(fmaxf(an2, 1e-12f));
    float term = fmaxf(ap - an + MARGIN, 0.0f);
    int cnt = (an >= ap) ? 1 : 0;
    #pragma unroll
    for (int m = 1; m < 64; m <<= 1) {
        term += __shfl_xor(term, m, 64);
        cnt  += __shfl_xor(cnt, m, 64);
    }
    __shared__ float sf[4];
    __shared__ int   si[4];
    if ((t & 63) == 0) { sf[t >> 6] = term; si[t >> 6] = cnt; }
    __syncthreads();
    if (t == 0) {
        atomicAdd(accF, sf[0] + sf[1] + sf[2] + sf[3]);
        atomicAdd(accI, si[0] + si[1] + si[2] + si[3]);
        __threadfence();
        int old = atomicAdd(tick, 1);
        if (old == gridDim.x - 1) {
            __threadfence();
            float S = atomicAdd(accF, 0.0f);
            int   C = atomicAdd(accI, 0);
            out[0] = S / (float)N_TOTAL;
            out[1] = (float)C;
        }
    }
}

extern "C" void kernel_launch(void* const* d_in, const int* in_sizes, int n_in,
                              void* d_out, int out_size, void* d_ws, size_t ws_size,
                              hipStream_t stream) {
    const float* X       = (const float*)d_in[0];   // [16384,128] fp32
    const int*   targets = (const int*)d_in[1];     // [16384] int32
    float* out = (float*)d_out;                     // [2]: loss, correct

    char* ws = (char*)d_ws;
    const size_t XB_BYTES = (size_t)N_TOTAL * FEAT * 2;              // 4 MB
    unsigned* Xb  = (unsigned*)ws;
    float* sq     = (float*)(ws + XB_BYTES);                         // 64 KB
    int* labs     = (int*)(ws + XB_BYTES + 1 * 65536);               // 64 KB
    float* pmin   = (float*)(ws + XB_BYTES + 2 * 65536);             // 512 KB
    float* pmax   = (float*)(ws + XB_BYTES + 2 * 65536 + 8 * N_TOTAL * 4); // 512 KB
    int* cursor   = (int*)(ws + XB_BYTES + 2 * 65536 + 16 * N_TOTAL * 4);  // 8 KB
    int* accs     = cursor + 2 * NBINS;                              // 12 B

    histscan_kernel<<<2, 1024, 0, stream>>>(targets, cursor, accs);
    prep_kernel    <<<4096, 256, 0, stream>>>(X, targets, cursor, Xb, sq, labs);
    cross_kernel   <<<512, 256, 0, stream>>>(
        (const unsigned short*)Xb, sq, labs, pmin, pmax);
    final_kernel   <<<64, 256, 0, stream>>>(pmin, pmax, accs, out);
}